// Round 14
// baseline (332.221 us; speedup 1.0000x reference)
//
#include <hip/hip_runtime.h>
#include <hip/hip_bf16.h>

typedef __attribute__((ext_vector_type(8))) short bf16x8;   // 8 bf16 in 4 VGPRs (MFMA A/B frag)
typedef __attribute__((ext_vector_type(4))) float f32x4;    // MFMA C/D frag

__device__ __forceinline__ unsigned short f2bf(float f) {   // RNE fp32->bf16
    unsigned u = __float_as_uint(f);
    u += 0x7fff + ((u >> 16) & 1);
    return (unsigned short)(u >> 16);
}
__device__ __forceinline__ float bf2f(unsigned short s) {
    return __uint_as_float(((unsigned)s) << 16);
}

#define GL2LDS16(g, l) __builtin_amdgcn_global_load_lds(                      \
        (const __attribute__((address_space(1))) void*)(g),                   \
        (__attribute__((address_space(3))) void*)(l), 16, 0, 0)

// ---------------- fused setup: CSR fill + wfuse + W2 transpose + zero-row + zero-pool + x->bf16 ----
// (R11-proven arrangement: atomic fill first, serial wfuse, streaming last)

__global__ __launch_bounds__(256) void fused_misc_kernel(
        const float* __restrict__ W2, unsigned short* __restrict__ Wt2,
        const float* __restrict__ x, unsigned short* __restrict__ xb, int n4,
        const float* __restrict__ W_in, const float* __restrict__ b_in,
        const float* __restrict__ W1,
        unsigned short* __restrict__ WfT, float* __restrict__ bv,
        const int* __restrict__ src, const int* __restrict__ dst,
        int* __restrict__ cursor, unsigned short* __restrict__ csr16,
        unsigned short* __restrict__ zrow,   // bufB row N (512 B)
        float* __restrict__ sums, int* __restrict__ counts,
        int e, int FB, int WB) {
    __shared__ float row[256];
    __shared__ unsigned short tile[64][65];
    int b = blockIdx.x;
    if (b < FB) {
        // padded-CSR fill: 64-slot segments; cursor doubles as degree count.
        int i = b * 256 + threadIdx.x;
        if (i < e) {
            int d = dst[i];
            int p = atomicAdd(&cursor[d], 1);
            if (p < 64) csr16[((size_t)d << 6) + p] = (unsigned short)src[i];
        }
    } else if (b < FB + WB) {
        // Wf = W_in @ W1 (bf16, transposed [n][k]); bv = b_in @ W1
        int k = b - FB;            // 0..127 -> WfT row k ; 128 -> bv
        int nn = threadIdx.x;
        row[nn] = (k < 128) ? W_in[k * 256 + nn] : b_in[nn];
        __syncthreads();
        float acc = 0.f;
        #pragma unroll 4
        for (int j = 0; j < 256; ++j) acc = fmaf(row[j], W1[j * 256 + nn], acc);
        if (k < 128) WfT[(size_t)nn * 128 + k] = f2bf(acc);
        else bv[nn] = acc;
    } else if (b < FB + WB + 16) {
        // Wt2[n][k] = bf16(W2[k][n]) via 64x64 LDS tile; coalesced both sides
        int t = b - FB - WB;
        int ti = t >> 2, tj = t & 3;
        int rq = threadIdx.x >> 4;
        int c0 = (threadIdx.x & 15) * 4;
        #pragma unroll
        for (int rr = 0; rr < 64; rr += 16) {
            int r = rr + rq;
            float4 v = *(const float4*)&W2[(size_t)(ti * 64 + r) * 256 + tj * 64 + c0];
            tile[r][c0]     = f2bf(v.x);
            tile[r][c0 + 1] = f2bf(v.y);
            tile[r][c0 + 2] = f2bf(v.z);
            tile[r][c0 + 3] = f2bf(v.w);
        }
        __syncthreads();
        #pragma unroll
        for (int rr = 0; rr < 64; rr += 16) {
            int nrow = rr + rq;
            ushort4 o;
            o.x = tile[c0][nrow];
            o.y = tile[c0 + 1][nrow];
            o.z = tile[c0 + 2][nrow];
            o.w = tile[c0 + 3][nrow];
            *(ushort4*)&Wt2[(size_t)(tj * 64 + nrow) * 256 + ti * 64 + c0] = o;
        }
    } else if (b == FB + WB + 16) {
        if (threadIdx.x < 128) ((unsigned*)zrow)[threadIdx.x] = 0u;
    } else if (b < FB + WB + 16 + 1 + 129) {
        int j = b - (FB + WB + 17);
        if (j < 128) sums[j * 256 + threadIdx.x] = 0.f;
        else if (threadIdx.x < 128) counts[threadIdx.x] = 0;
    } else {
        int i = (b - FB - WB - 17 - 129) * 256 + threadIdx.x;
        if (i < n4) {
            float4 v = ((const float4*)x)[i];
            ushort4 o;
            o.x = f2bf(v.x); o.y = f2bf(v.y); o.z = f2bf(v.z); o.w = f2bf(v.w);
            ((ushort4*)xb)[i] = o;
        }
    }
}

// ---------------- bf16 MFMA GEMM, B-RESIDENT: C[M,256] = A[M,KT] @ W[KT,256] ----------------
// B ([256][KT] transposed weights) staged ONCE into LDS; A double-buffered 64x64 tiles.
// One barrier per K-step (A-stage for t+1 issued before compute of t, drained at barrier).
// BM=64 x BN=256, 512 threads = 8 waves (2x4), each wave 32x64 out (acc[2][4]).
// LDS: A dbuf 16 KB + B KT*512 B = 80 KB (KT=128) / 144 KB (KT=256).
// MODE 0: +bias[col]
// MODE 1: *rsqrt(deg[row]+1)   (aux reinterpreted as const int* degree)
// MODE 2: relu(acc + s[row]*bv[col] + b[col])

template <int MODE, int KT>
__global__ __launch_bounds__(512) void gemm_bf16(const unsigned short* __restrict__ A,
                                                 const unsigned short* __restrict__ Wt,
                                                 const float* __restrict__ aux,
                                                 const float* __restrict__ aux2,
                                                 const float* __restrict__ aux3,
                                                 unsigned short* __restrict__ C,
                                                 int M) {
    __shared__ unsigned short S[8192 + 256 * KT];  // [0,8192): A dbuf 2x[64][64]; [8192,..): B [256][KT]
    const int tid  = threadIdx.x;
    const int lane = tid & 63;
    const int w    = tid >> 6;                // 0..7
    const int wr   = w >> 2, wc = w & 3;      // 2 x 4 wave grid
    const int row0 = blockIdx.x * 64;
    const int mlane = lane & 15, quad = lane >> 4;

    f32x4 acc[2][4];
    #pragma unroll
    for (int i = 0; i < 2; ++i)
        #pragma unroll
        for (int j = 0; j < 4; ++j) acc[i][j] = f32x4{0.f, 0.f, 0.f, 0.f};

    // ---- prologue: stage all of B (32*KT/512 chunks/thread) + A tile 0 (1 chunk/thread)
    constexpr int BPT = (32 * KT) / 512;      // 8 (KT=128) or 16 (KT=256)
    #pragma unroll
    for (int q = 0; q < BPT; ++q) {
        int cid = q * 512 + tid;              // B chunk id; LDS offset = cid*8 shorts (linear)
        int col = cid / (KT / 8), slot = cid % (KT / 8);
        GL2LDS16(Wt + (size_t)col * KT + slot * 8, &S[8192 + (q * 512 + w * 64) * 8]);
    }
    const unsigned short* gA;
    {
        int r = tid >> 3, slot = tid & 7;     // 64 rows x 8 slots
        int rowA = row0 + r; if (rowA >= M) rowA = M - 1;
        gA = A + (size_t)rowA * KT + slot * 8;
        GL2LDS16(gA, &S[(w * 64) * 8]);       // buffer 0
    }
    __syncthreads();

    // ---- K-loop: one barrier per step; A-stage for t+1 in flight during compute of t
    #pragma unroll
    for (int t = 0; t < KT / 64; ++t) {
        if (t + 1 < KT / 64)
            GL2LDS16(gA + (t + 1) * 64, &S[((t + 1) & 1) * 4096 + (w * 64) * 8]);
        const int abase = (t & 1) * 4096;
        #pragma unroll
        for (int ks = 0; ks < 2; ++ks) {
            bf16x8 af[2], bfv[4];
            #pragma unroll
            for (int i = 0; i < 2; ++i)
                af[i] = *(const bf16x8*)&S[abase + (wr * 32 + i * 16 + mlane) * 64 + ks * 32 + quad * 8];
            #pragma unroll
            for (int j = 0; j < 4; ++j)
                bfv[j] = *(const bf16x8*)&S[8192 + (wc * 64 + j * 16 + mlane) * KT + t * 64 + ks * 32 + quad * 8];
            #pragma unroll
            for (int i = 0; i < 2; ++i)
                #pragma unroll
                for (int j = 0; j < 4; ++j)
                    acc[i][j] = __builtin_amdgcn_mfma_f32_16x16x32_bf16(af[i], bfv[j], acc[i][j], 0, 0, 0);
        }
        __syncthreads();
    }

    // ---- epilogue
    float bj[4], cj[4];
    if (MODE == 0) {
        #pragma unroll
        for (int j = 0; j < 4; ++j) bj[j] = aux[wc * 64 + j * 16 + mlane];
    } else if (MODE == 2) {
        #pragma unroll
        for (int j = 0; j < 4; ++j) {
            int gcol = wc * 64 + j * 16 + mlane;
            bj[j] = aux2[gcol];
            cj[j] = aux3[gcol];
        }
    }
    #pragma unroll
    for (int i = 0; i < 2; ++i) {
        #pragma unroll
        for (int r = 0; r < 4; ++r) {
            int grow = row0 + wr * 32 + i * 16 + quad * 4 + r;
            if (grow < M) {
                float d = 0.f;
                if (MODE == 1) d = rsqrtf((float)((const int*)aux)[grow] + 1.0f);
                else if (MODE == 2) d = aux[grow];
                #pragma unroll
                for (int j = 0; j < 4; ++j) {
                    int gcol = wc * 64 + j * 16 + mlane;
                    float v = acc[i][j][r];
                    if (MODE == 0)      v = v + bj[j];
                    else if (MODE == 1) v = v * d;
                    else {              v = fmaf(d, bj[j], v) + cj[j]; v = fmaxf(v, 0.f); }
                    C[(size_t)grow * 256 + gcol] = f2bf(v);
                }
            }
        }
    }
}

// ---------------- layer-1 aggregation over raw x (128-wide), dinv-weighted gather ----------------
// (R10-proven, unchanged)

__global__ __launch_bounds__(256) void agg_x_kernel(const unsigned short* __restrict__ xb,
                                                    const int* __restrict__ deg,
                                                    const unsigned short* __restrict__ csr16,
                                                    unsigned short* __restrict__ ax,
                                                    float* __restrict__ s_out, int n) {
    int node = blockIdx.x * 4 + (threadIdx.x >> 6);
    if (node >= n) return;
    int lane = threadIdx.x & 63;
    int half = lane >> 5, hl = lane & 31;
    const ushort4* x4 = (const ushort4*)xb;   // 32 ushort4 per 128-wide row
    int cnt = deg[node]; if (cnt > 64) cnt = 64;
    size_t beg = (size_t)node << 6;
    float dn = rsqrtf((float)deg[node] + 1.0f);
    float a0 = 0.f, a1 = 0.f, a2 = 0.f, a3 = 0.f;
    float sdl = 0.f;

    int myi = 0; float mydv = 0.f;
    if (lane < cnt) {
        myi = (int)csr16[beg + lane];
        mydv = rsqrtf((float)deg[myi] + 1.0f);
        sdl += mydv;
    }
    for (int j = 0; j < cnt; j += 8) {
        int s0 = __shfl(myi, j + half),     s1 = __shfl(myi, j + 2 + half);
        int s2 = __shfl(myi, j + 4 + half), s3 = __shfl(myi, j + 6 + half);
        float d0 = __shfl(mydv, j + half),     d1 = __shfl(mydv, j + 2 + half);
        float d2 = __shfl(mydv, j + 4 + half), d3 = __shfl(mydv, j + 6 + half);
        ushort4 v0 = x4[(size_t)s0 * 32 + hl];
        ushort4 v1 = x4[(size_t)s1 * 32 + hl];
        ushort4 v2 = x4[(size_t)s2 * 32 + hl];
        ushort4 v3 = x4[(size_t)s3 * 32 + hl];
        a0 = fmaf(bf2f(v0.x), d0, a0); a1 = fmaf(bf2f(v0.y), d0, a1);
        a2 = fmaf(bf2f(v0.z), d0, a2); a3 = fmaf(bf2f(v0.w), d0, a3);
        a0 = fmaf(bf2f(v1.x), d1, a0); a1 = fmaf(bf2f(v1.y), d1, a1);
        a2 = fmaf(bf2f(v1.z), d1, a2); a3 = fmaf(bf2f(v1.w), d1, a3);
        a0 = fmaf(bf2f(v2.x), d2, a0); a1 = fmaf(bf2f(v2.y), d2, a1);
        a2 = fmaf(bf2f(v2.z), d2, a2); a3 = fmaf(bf2f(v2.w), d2, a3);
        a0 = fmaf(bf2f(v3.x), d3, a0); a1 = fmaf(bf2f(v3.y), d3, a1);
        a2 = fmaf(bf2f(v3.z), d3, a2); a3 = fmaf(bf2f(v3.w), d3, a3);
    }

    a0 += __shfl_xor(a0, 32); a1 += __shfl_xor(a1, 32);
    a2 += __shfl_xor(a2, 32); a3 += __shfl_xor(a3, 32);
    float sd = sdl;
    #pragma unroll
    for (int off = 32; off > 0; off >>= 1) sd += __shfl_down(sd, off);
    if (lane < 32) {
        ushort4 sv = x4[(size_t)node * 32 + hl];
        a0 = fmaf(dn, bf2f(sv.x), a0) * dn;
        a1 = fmaf(dn, bf2f(sv.y), a1) * dn;
        a2 = fmaf(dn, bf2f(sv.z), a2) * dn;
        a3 = fmaf(dn, bf2f(sv.w), a3) * dn;
        ushort4 r;
        r.x = f2bf(a0); r.y = f2bf(a1); r.z = f2bf(a2); r.w = f2bf(a3);
        ((ushort4*)ax)[(size_t)node * 32 + hl] = r;
        if (lane == 0) s_out[node] = dn * (sd + dn);
    }
}

// ---------------- layer-2 aggregation (256-wide), full-wave 8-deep gather ----------------
// (R10-proven, unchanged)

__global__ __launch_bounds__(256) void agg_kernel(const unsigned short* __restrict__ hs,
                                                  const int* __restrict__ deg,
                                                  const unsigned short* __restrict__ csr16,
                                                  const float* __restrict__ bias,
                                                  unsigned short* __restrict__ out, int n) {
    int node = blockIdx.x * 4 + (threadIdx.x >> 6);
    if (node >= n) return;
    int lane = threadIdx.x & 63;
    const ushort4* hs4 = (const ushort4*)hs;
    int cnt = deg[node]; if (cnt > 64) cnt = 64;
    size_t beg = (size_t)node << 6;
    ushort4 sv = hs4[(size_t)node * 64 + lane];
    float a0 = bf2f(sv.x), a1 = bf2f(sv.y), a2 = bf2f(sv.z), a3 = bf2f(sv.w);
    float c0 = 0.f, c1 = 0.f, c2 = 0.f, c3 = 0.f;

    int myi = (lane < cnt) ? (int)csr16[beg + lane] : n;   // pad -> zero row
    for (int j = 0; j < cnt; j += 8) {
        int s0 = __shfl(myi, j + 0), s1 = __shfl(myi, j + 1);
        int s2 = __shfl(myi, j + 2), s3 = __shfl(myi, j + 3);
        int s4 = __shfl(myi, j + 4), s5 = __shfl(myi, j + 5);
        int s6 = __shfl(myi, j + 6), s7 = __shfl(myi, j + 7);
        ushort4 v0 = hs4[(size_t)s0 * 64 + lane];
        ushort4 v1 = hs4[(size_t)s1 * 64 + lane];
        ushort4 v2 = hs4[(size_t)s2 * 64 + lane];
        ushort4 v3 = hs4[(size_t)s3 * 64 + lane];
        ushort4 v4 = hs4[(size_t)s4 * 64 + lane];
        ushort4 v5 = hs4[(size_t)s5 * 64 + lane];
        ushort4 v6 = hs4[(size_t)s6 * 64 + lane];
        ushort4 v7 = hs4[(size_t)s7 * 64 + lane];
        a0 += bf2f(v0.x) + bf2f(v1.x) + bf2f(v2.x) + bf2f(v3.x);
        a1 += bf2f(v0.y) + bf2f(v1.y) + bf2f(v2.y) + bf2f(v3.y);
        a2 += bf2f(v0.z) + bf2f(v1.z) + bf2f(v2.z) + bf2f(v3.z);
        a3 += bf2f(v0.w) + bf2f(v1.w) + bf2f(v2.w) + bf2f(v3.w);
        c0 += bf2f(v4.x) + bf2f(v5.x) + bf2f(v6.x) + bf2f(v7.x);
        c1 += bf2f(v4.y) + bf2f(v5.y) + bf2f(v6.y) + bf2f(v7.y);
        c2 += bf2f(v4.z) + bf2f(v5.z) + bf2f(v6.z) + bf2f(v7.z);
        c3 += bf2f(v4.w) + bf2f(v5.w) + bf2f(v6.w) + bf2f(v7.w);
    }
    a0 += c0; a1 += c1; a2 += c2; a3 += c3;

    float d = rsqrtf((float)deg[node] + 1.0f);
    float4 b = ((const float4*)bias)[lane];
    ushort4 r;
    r.x = f2bf(fmaxf(fmaf(a0, d, b.x), 0.f));
    r.y = f2bf(fmaxf(fmaf(a1, d, b.y), 0.f));
    r.z = f2bf(fmaxf(fmaf(a2, d, b.z), 0.f));
    r.w = f2bf(fmaxf(fmaf(a3, d, b.w), 0.f));
    ((ushort4*)out)[(size_t)node * 64 + lane] = r;
}

// ---------------- pooling (known-good split) ----------------

__global__ __launch_bounds__(256) void pool_partial_kernel(const unsigned short* __restrict__ h,
                                                           const int* __restrict__ batch,
                                                           float* __restrict__ sums,
                                                           int* __restrict__ counts,
                                                           int n, int chunk) {
    int beg = blockIdx.x * chunk;
    int end = beg + chunk; if (end > n) end = n;
    if (beg >= end) return;
    int c = threadIdx.x;
    int curg = batch[beg];
    float acc = 0.f;
    int runlen = 0;
    for (int i = beg; i < end; ++i) {
        int g = batch[i];
        if (g != curg) {
            atomicAdd(&sums[(size_t)curg * 256 + c], acc);
            if (c == 0) atomicAdd(&counts[curg], runlen);
            acc = 0.f; runlen = 0; curg = g;
        }
        acc += bf2f(h[(size_t)i * 256 + c]);
        ++runlen;
    }
    atomicAdd(&sums[(size_t)curg * 256 + c], acc);
    if (c == 0) atomicAdd(&counts[curg], runlen);
}

__global__ __launch_bounds__(256) void pool_final_kernel(const float* __restrict__ sums,
                                                         const int* __restrict__ counts,
                                                         const float* __restrict__ Wout,
                                                         const float* __restrict__ bout,
                                                         float* __restrict__ out) {
    __shared__ float pl[256];
    int g = blockIdx.x;
    int c = threadIdx.x;
    int cnt = counts[g];
    pl[c] = sums[(size_t)g * 256 + c] / (float)(cnt > 0 ? cnt : 1);
    __syncthreads();
    if (c < 16) {
        float o = bout[c];
        #pragma unroll 4
        for (int k = 0; k < 256; ++k) o = fmaf(pl[k], Wout[k * 16 + c], o);
        out[g * 16 + c] = o;
    }
}

// ---------------- launch ----------------

extern "C" void kernel_launch(void* const* d_in, const int* in_sizes, int n_in,
                              void* d_out, int out_size, void* d_ws, size_t ws_size,
                              hipStream_t stream) {
    const float* x     = (const float*)d_in[0];
    const int*   ei    = (const int*)d_in[1];
    const int*   batch = (const int*)d_in[2];
    const float* W_in  = (const float*)d_in[3];
    const float* b_in  = (const float*)d_in[4];
    const float* W1    = (const float*)d_in[5];
    const float* b1    = (const float*)d_in[6];
    const float* W2    = (const float*)d_in[7];
    const float* b2    = (const float*)d_in[8];
    const float* Wout  = (const float*)d_in[9];
    const float* bout  = (const float*)d_in[10];

    const int E = in_sizes[1] / 2;
    const int N = in_sizes[2];
    const int IN_DIM = in_sizes[0] / N;   // 128
    const int G = 128;
    const int* src = ei;
    const int* dst = ei + E;

    char* ws = (char*)d_ws;
    size_t off = 0;
    auto alloc = [&](size_t bytes) { size_t p = off; off += (bytes + 255) & ~(size_t)255; return p; };
    unsigned short* bufA = (unsigned short*)(ws + alloc((size_t)N * 256 * 2));
    unsigned short* bufB = (unsigned short*)(ws + alloc((size_t)(N + 1) * 256 * 2)); // +1 zero row
    unsigned short* xb   = (unsigned short*)(ws + alloc((size_t)N * IN_DIM * 2));
    unsigned short* Wt2  = (unsigned short*)(ws + alloc((size_t)256 * 256 * 2));
    unsigned short* WfT  = (unsigned short*)(ws + alloc((size_t)256 * IN_DIM * 2));
    float*          bv   = (float*)(ws + alloc((size_t)256 * 4));
    float*          sbuf = (float*)(ws + alloc((size_t)N * 4));
    float* sums    = (float*)(ws + alloc((size_t)G * 256 * 4));
    int*   counts  = (int*)(ws + alloc((size_t)G * 4));
    size_t zbeg = off;
    int*   cursor  = (int*)(ws + alloc((size_t)N * 4));
    size_t zend = off;
    unsigned short* csr16 = (unsigned short*)(ws + alloc((size_t)N * 64 * 2));
    (void)ws_size;

    // ax aliases bufB's low region (dead until layer-2 gemm writes it); zero row beyond.
    unsigned short* axb = bufB;
    unsigned short* zrow = bufB + (size_t)N * 256;

    const int XB  = (N * IN_DIM / 4 + 255) / 256;
    const int WB  = 129;
    const int FB  = (E + 255) / 256;
    const int SB  = 129;   // sums+counts zeroing
    const int MB  = (N + 63) / 64;   // 782 gemm blocks

    hipMemsetAsync(ws + zbeg, 0, zend - zbeg, stream);   // cursor only (200 KB)
    fused_misc_kernel<<<FB + WB + 16 + 1 + SB + XB, 256, 0, stream>>>(
        W2, Wt2, x, xb, N * IN_DIM / 4, W_in, b_in, W1, WfT, bv,
        src, dst, cursor, csr16, zrow, sums, counts, E, FB, WB);

    // layer 1: aggregate raw x (128-wide), then one fused GEMM with relu epilogue
    agg_x_kernel<<<(N + 3) / 4, 256, 0, stream>>>(xb, cursor, csr16, axb, sbuf, N);
    gemm_bf16<2, 128><<<MB, 512, 0, stream>>>(axb, WfT, sbuf, bv, b1, bufA, N);

    // layer 2: gemm (deg-normalized epilogue) then aggregation with relu+bias
    gemm_bf16<1, 256><<<MB, 512, 0, stream>>>(bufA, Wt2, (const float*)cursor, nullptr, nullptr, bufB, N);
    agg_kernel<<<(N + 3) / 4, 256, 0, stream>>>(bufB, cursor, csr16, b2, bufA, N);

    const int PBLOCKS = 512;
    int chunk = (N + PBLOCKS - 1) / PBLOCKS;
    pool_partial_kernel<<<PBLOCKS, 256, 0, stream>>>(bufA, batch, sums, counts, N, chunk);
    pool_final_kernel<<<G, 256, 0, stream>>>(sums, counts, Wout, bout, (float*)d_out);
}

// Round 15
// 315.117 us; speedup vs baseline: 1.0543x; 1.0543x over previous
//
#include <hip/hip_runtime.h>
#include <hip/hip_bf16.h>

typedef __attribute__((ext_vector_type(8))) short bf16x8;   // 8 bf16 in 4 VGPRs (MFMA A/B frag)
typedef __attribute__((ext_vector_type(4))) float f32x4;    // MFMA C/D frag

__device__ __forceinline__ unsigned short f2bf(float f) {   // RNE fp32->bf16
    unsigned u = __float_as_uint(f);
    u += 0x7fff + ((u >> 16) & 1);
    return (unsigned short)(u >> 16);
}
__device__ __forceinline__ float bf2f(unsigned short s) {
    return __uint_as_float(((unsigned)s) << 16);
}

#define GL2LDS16(g, l) __builtin_amdgcn_global_load_lds(                      \
        (const __attribute__((address_space(1))) void*)(g),                   \
        (__attribute__((address_space(3))) void*)(l), 16, 0, 0)

// ---------------- fused setup: CSR fill + wfuse + W2 transpose + zero-row + zero-pool + x->bf16 ----
// Section order: atomic-latency-bound fill FIRST (its stalls overlap everything else),
// then serial wfuse, then streaming.

__global__ __launch_bounds__(256) void fused_misc_kernel(
        const float* __restrict__ W2, unsigned short* __restrict__ Wt2,
        const float* __restrict__ x, unsigned short* __restrict__ xb, int n4,
        const float* __restrict__ W_in, const float* __restrict__ b_in,
        const float* __restrict__ W1,
        unsigned short* __restrict__ WfT, float* __restrict__ bv,
        const int* __restrict__ src, const int* __restrict__ dst,
        int* __restrict__ cursor, unsigned short* __restrict__ csr16,
        unsigned short* __restrict__ zrow,   // bufB row N (512 B)
        float* __restrict__ sums, int* __restrict__ counts,
        int e, int FB, int WB) {
    __shared__ float row[256];
    __shared__ unsigned short tile[64][65];
    int b = blockIdx.x;
    if (b < FB) {
        // padded-CSR fill: 64-slot segments; cursor doubles as degree count.
        // P(deg>64) ~ 1e-20 for Poisson(16); clamp drops an edge in worst case.
        int i = b * 256 + threadIdx.x;
        if (i < e) {
            int d = dst[i];
            int p = atomicAdd(&cursor[d], 1);
            if (p < 64) csr16[((size_t)d << 6) + p] = (unsigned short)src[i];
        }
    } else if (b < FB + WB) {
        // Wf = W_in @ W1 (bf16, transposed [n][k]); bv = b_in @ W1
        int k = b - FB;            // 0..127 -> WfT row k ; 128 -> bv
        int nn = threadIdx.x;
        row[nn] = (k < 128) ? W_in[k * 256 + nn] : b_in[nn];
        __syncthreads();
        float acc = 0.f;
        #pragma unroll 4
        for (int j = 0; j < 256; ++j) acc = fmaf(row[j], W1[j * 256 + nn], acc);
        if (k < 128) WfT[(size_t)nn * 128 + k] = f2bf(acc);
        else bv[nn] = acc;
    } else if (b < FB + WB + 16) {
        // Wt2[n][k] = bf16(W2[k][n]) via 64x64 LDS tile; coalesced both sides
        int t = b - FB - WB;
        int ti = t >> 2, tj = t & 3;
        int rq = threadIdx.x >> 4;
        int c0 = (threadIdx.x & 15) * 4;
        #pragma unroll
        for (int rr = 0; rr < 64; rr += 16) {
            int r = rr + rq;
            float4 v = *(const float4*)&W2[(size_t)(ti * 64 + r) * 256 + tj * 64 + c0];
            tile[r][c0]     = f2bf(v.x);
            tile[r][c0 + 1] = f2bf(v.y);
            tile[r][c0 + 2] = f2bf(v.z);
            tile[r][c0 + 3] = f2bf(v.w);
        }
        __syncthreads();
        #pragma unroll
        for (int rr = 0; rr < 64; rr += 16) {
            int nrow = rr + rq;
            ushort4 o;
            o.x = tile[c0][nrow];
            o.y = tile[c0 + 1][nrow];
            o.z = tile[c0 + 2][nrow];
            o.w = tile[c0 + 3][nrow];
            *(ushort4*)&Wt2[(size_t)(tj * 64 + nrow) * 256 + ti * 64 + c0] = o;
        }
    } else if (b == FB + WB + 16) {
        if (threadIdx.x < 128) ((unsigned*)zrow)[threadIdx.x] = 0u;
    } else if (b < FB + WB + 16 + 1 + 129) {
        int j = b - (FB + WB + 17);
        if (j < 128) sums[j * 256 + threadIdx.x] = 0.f;
        else if (threadIdx.x < 128) counts[threadIdx.x] = 0;
    } else {
        int i = (b - FB - WB - 17 - 129) * 256 + threadIdx.x;
        if (i < n4) {
            float4 v = ((const float4*)x)[i];
            ushort4 o;
            o.x = f2bf(v.x); o.y = f2bf(v.y); o.z = f2bf(v.z); o.w = f2bf(v.w);
            ((ushort4*)xb)[i] = o;
        }
    }
}

// ---------------- bf16 MFMA GEMM: C[M,256] = A[M,K] @ W[K,256] ----------------
// (R11-proven config, best measured) 512-thread blocks, BM=128 x BN=256: A read ONCE,
// 391 blocks, 8 waves as 2x4, each wave 64x64 out (4x4 acc). LDS 48 KB.
// MODE 0: +bias[col]
// MODE 1: *rsqrt(deg[row]+1)   (aux reinterpreted as const int* degree)
// MODE 2: relu(acc + s[row]*bv[col] + b[col])

template <int MODE>
__global__ __launch_bounds__(512) void gemm_bf16(const unsigned short* __restrict__ A,
                                                 const unsigned short* __restrict__ Wt,
                                                 const float* __restrict__ aux,
                                                 const float* __restrict__ aux2,
                                                 const float* __restrict__ aux3,
                                                 unsigned short* __restrict__ C,
                                                 int M, int K) {
    __shared__ unsigned short S[3072 * 8];    // As: [0,8192) = 128x64 ; Bs: [8192, 24576) = 256x64
    const int tid  = threadIdx.x;
    const int lane = tid & 63;
    const int w    = tid >> 6;                // 0..7
    const int wr   = w >> 2, wc = w & 3;      // 2 x 4 wave grid
    const int row0 = blockIdx.x * 128;
    const int mlane = lane & 15, quad = lane >> 4;

    f32x4 acc[4][4];
    #pragma unroll
    for (int i = 0; i < 4; ++i)
        #pragma unroll
        for (int j = 0; j < 4; ++j) acc[i][j] = f32x4{0.f, 0.f, 0.f, 0.f};

    // staging: 3072 16B-chunks per K-step; 6 chunks/thread; wave-uniform LDS bases
    const unsigned short* g[6]; unsigned short* l[6];
    #pragma unroll
    for (int q = 0; q < 6; ++q) {
        int cid = q * 512 + tid;              // 0..3071 ; wave-uniform A/B split (64-aligned)
        l[q] = &S[(q * 512 + w * 64) * 8];
        if (cid < 1024) {                     // A: 128 rows x 8 slots
            int r = cid >> 3, slot = cid & 7;
            int rowA = row0 + r; if (rowA >= M) rowA = M - 1;
            g[q] = A + (size_t)rowA * K + slot * 8;
        } else {                              // B: 256 cols x 8 slots
            int j = cid - 1024;
            int col = j >> 3, slot = j & 7;
            g[q] = Wt + (size_t)col * K + slot * 8;
        }
    }

    for (int k0 = 0; k0 < K; k0 += 64) {
        #pragma unroll
        for (int q = 0; q < 6; ++q) GL2LDS16(g[q] + k0, l[q]);
        __syncthreads();
        #pragma unroll
        for (int ks = 0; ks < 2; ++ks) {
            bf16x8 af[4], bfv[4];
            #pragma unroll
            for (int i = 0; i < 4; ++i)
                af[i] = *(const bf16x8*)&S[(wr * 64 + i * 16 + mlane) * 64 + ks * 32 + quad * 8];
            #pragma unroll
            for (int j = 0; j < 4; ++j)
                bfv[j] = *(const bf16x8*)&S[8192 + (wc * 64 + j * 16 + mlane) * 64 + ks * 32 + quad * 8];
            #pragma unroll
            for (int i = 0; i < 4; ++i)
                #pragma unroll
                for (int j = 0; j < 4; ++j)
                    acc[i][j] = __builtin_amdgcn_mfma_f32_16x16x32_bf16(af[i], bfv[j], acc[i][j], 0, 0, 0);
        }
        __syncthreads();
    }

    float bj[4], cj[4];
    if (MODE == 0) {
        #pragma unroll
        for (int j = 0; j < 4; ++j) bj[j] = aux[wc * 64 + j * 16 + mlane];
    } else if (MODE == 2) {
        #pragma unroll
        for (int j = 0; j < 4; ++j) {
            int gcol = wc * 64 + j * 16 + mlane;
            bj[j] = aux2[gcol];
            cj[j] = aux3[gcol];
        }
    }
    #pragma unroll
    for (int i = 0; i < 4; ++i) {
        #pragma unroll
        for (int r = 0; r < 4; ++r) {
            int grow = row0 + wr * 64 + i * 16 + quad * 4 + r;
            if (grow < M) {
                float d = 0.f;
                if (MODE == 1) d = rsqrtf((float)((const int*)aux)[grow] + 1.0f);
                else if (MODE == 2) d = aux[grow];
                #pragma unroll
                for (int j = 0; j < 4; ++j) {
                    int gcol = wc * 64 + j * 16 + mlane;
                    float v = acc[i][j][r];
                    if (MODE == 0)      v = v + bj[j];
                    else if (MODE == 1) v = v * d;
                    else {              v = fmaf(d, bj[j], v) + cj[j]; v = fmaxf(v, 0.f); }
                    C[(size_t)grow * 256 + gcol] = f2bf(v);
                }
            }
        }
    }
}

// ---------------- layer-1 aggregation over raw x (128-wide), dinv-weighted gather ----------------
// (R10-proven, unchanged)

__global__ __launch_bounds__(256) void agg_x_kernel(const unsigned short* __restrict__ xb,
                                                    const int* __restrict__ deg,
                                                    const unsigned short* __restrict__ csr16,
                                                    unsigned short* __restrict__ ax,
                                                    float* __restrict__ s_out, int n) {
    int node = blockIdx.x * 4 + (threadIdx.x >> 6);
    if (node >= n) return;
    int lane = threadIdx.x & 63;
    int half = lane >> 5, hl = lane & 31;
    const ushort4* x4 = (const ushort4*)xb;   // 32 ushort4 per 128-wide row
    int cnt = deg[node]; if (cnt > 64) cnt = 64;
    size_t beg = (size_t)node << 6;
    float dn = rsqrtf((float)deg[node] + 1.0f);
    float a0 = 0.f, a1 = 0.f, a2 = 0.f, a3 = 0.f;
    float sdl = 0.f;

    int myi = 0; float mydv = 0.f;
    if (lane < cnt) {
        myi = (int)csr16[beg + lane];
        mydv = rsqrtf((float)deg[myi] + 1.0f);
        sdl += mydv;
    }
    for (int j = 0; j < cnt; j += 8) {
        int s0 = __shfl(myi, j + half),     s1 = __shfl(myi, j + 2 + half);
        int s2 = __shfl(myi, j + 4 + half), s3 = __shfl(myi, j + 6 + half);
        float d0 = __shfl(mydv, j + half),     d1 = __shfl(mydv, j + 2 + half);
        float d2 = __shfl(mydv, j + 4 + half), d3 = __shfl(mydv, j + 6 + half);
        ushort4 v0 = x4[(size_t)s0 * 32 + hl];
        ushort4 v1 = x4[(size_t)s1 * 32 + hl];
        ushort4 v2 = x4[(size_t)s2 * 32 + hl];
        ushort4 v3 = x4[(size_t)s3 * 32 + hl];
        a0 = fmaf(bf2f(v0.x), d0, a0); a1 = fmaf(bf2f(v0.y), d0, a1);
        a2 = fmaf(bf2f(v0.z), d0, a2); a3 = fmaf(bf2f(v0.w), d0, a3);
        a0 = fmaf(bf2f(v1.x), d1, a0); a1 = fmaf(bf2f(v1.y), d1, a1);
        a2 = fmaf(bf2f(v1.z), d1, a2); a3 = fmaf(bf2f(v1.w), d1, a3);
        a0 = fmaf(bf2f(v2.x), d2, a0); a1 = fmaf(bf2f(v2.y), d2, a1);
        a2 = fmaf(bf2f(v2.z), d2, a2); a3 = fmaf(bf2f(v2.w), d2, a3);
        a0 = fmaf(bf2f(v3.x), d3, a0); a1 = fmaf(bf2f(v3.y), d3, a1);
        a2 = fmaf(bf2f(v3.z), d3, a2); a3 = fmaf(bf2f(v3.w), d3, a3);
    }

    a0 += __shfl_xor(a0, 32); a1 += __shfl_xor(a1, 32);
    a2 += __shfl_xor(a2, 32); a3 += __shfl_xor(a3, 32);
    float sd = sdl;
    #pragma unroll
    for (int off = 32; off > 0; off >>= 1) sd += __shfl_down(sd, off);
    if (lane < 32) {
        ushort4 sv = x4[(size_t)node * 32 + hl];
        a0 = fmaf(dn, bf2f(sv.x), a0) * dn;
        a1 = fmaf(dn, bf2f(sv.y), a1) * dn;
        a2 = fmaf(dn, bf2f(sv.z), a2) * dn;
        a3 = fmaf(dn, bf2f(sv.w), a3) * dn;
        ushort4 r;
        r.x = f2bf(a0); r.y = f2bf(a1); r.z = f2bf(a2); r.w = f2bf(a3);
        ((ushort4*)ax)[(size_t)node * 32 + hl] = r;
        if (lane == 0) s_out[node] = dn * (sd + dn);
    }
}

// ---------------- layer-2 aggregation (256-wide), full-wave 8-deep gather ----------------
// (R10-proven, unchanged)

__global__ __launch_bounds__(256) void agg_kernel(const unsigned short* __restrict__ hs,
                                                  const int* __restrict__ deg,
                                                  const unsigned short* __restrict__ csr16,
                                                  const float* __restrict__ bias,
                                                  unsigned short* __restrict__ out, int n) {
    int node = blockIdx.x * 4 + (threadIdx.x >> 6);
    if (node >= n) return;
    int lane = threadIdx.x & 63;
    const ushort4* hs4 = (const ushort4*)hs;
    int cnt = deg[node]; if (cnt > 64) cnt = 64;
    size_t beg = (size_t)node << 6;
    ushort4 sv = hs4[(size_t)node * 64 + lane];
    float a0 = bf2f(sv.x), a1 = bf2f(sv.y), a2 = bf2f(sv.z), a3 = bf2f(sv.w);
    float c0 = 0.f, c1 = 0.f, c2 = 0.f, c3 = 0.f;

    int myi = (lane < cnt) ? (int)csr16[beg + lane] : n;   // pad -> zero row
    for (int j = 0; j < cnt; j += 8) {
        int s0 = __shfl(myi, j + 0), s1 = __shfl(myi, j + 1);
        int s2 = __shfl(myi, j + 2), s3 = __shfl(myi, j + 3);
        int s4 = __shfl(myi, j + 4), s5 = __shfl(myi, j + 5);
        int s6 = __shfl(myi, j + 6), s7 = __shfl(myi, j + 7);
        ushort4 v0 = hs4[(size_t)s0 * 64 + lane];
        ushort4 v1 = hs4[(size_t)s1 * 64 + lane];
        ushort4 v2 = hs4[(size_t)s2 * 64 + lane];
        ushort4 v3 = hs4[(size_t)s3 * 64 + lane];
        ushort4 v4 = hs4[(size_t)s4 * 64 + lane];
        ushort4 v5 = hs4[(size_t)s5 * 64 + lane];
        ushort4 v6 = hs4[(size_t)s6 * 64 + lane];
        ushort4 v7 = hs4[(size_t)s7 * 64 + lane];
        a0 += bf2f(v0.x) + bf2f(v1.x) + bf2f(v2.x) + bf2f(v3.x);
        a1 += bf2f(v0.y) + bf2f(v1.y) + bf2f(v2.y) + bf2f(v3.y);
        a2 += bf2f(v0.z) + bf2f(v1.z) + bf2f(v2.z) + bf2f(v3.z);
        a3 += bf2f(v0.w) + bf2f(v1.w) + bf2f(v2.w) + bf2f(v3.w);
        c0 += bf2f(v4.x) + bf2f(v5.x) + bf2f(v6.x) + bf2f(v7.x);
        c1 += bf2f(v4.y) + bf2f(v5.y) + bf2f(v6.y) + bf2f(v7.y);
        c2 += bf2f(v4.z) + bf2f(v5.z) + bf2f(v6.z) + bf2f(v7.z);
        c3 += bf2f(v4.w) + bf2f(v5.w) + bf2f(v6.w) + bf2f(v7.w);
    }
    a0 += c0; a1 += c1; a2 += c2; a3 += c3;

    float d = rsqrtf((float)deg[node] + 1.0f);
    float4 b = ((const float4*)bias)[lane];
    ushort4 r;
    r.x = f2bf(fmaxf(fmaf(a0, d, b.x), 0.f));
    r.y = f2bf(fmaxf(fmaf(a1, d, b.y), 0.f));
    r.z = f2bf(fmaxf(fmaf(a2, d, b.z), 0.f));
    r.w = f2bf(fmaxf(fmaf(a3, d, b.w), 0.f));
    ((ushort4*)out)[(size_t)node * 64 + lane] = r;
}

// ---------------- pooling (known-good split) ----------------

__global__ __launch_bounds__(256) void pool_partial_kernel(const unsigned short* __restrict__ h,
                                                           const int* __restrict__ batch,
                                                           float* __restrict__ sums,
                                                           int* __restrict__ counts,
                                                           int n, int chunk) {
    int beg = blockIdx.x * chunk;
    int end = beg + chunk; if (end > n) end = n;
    if (beg >= end) return;
    int c = threadIdx.x;
    int curg = batch[beg];
    float acc = 0.f;
    int runlen = 0;
    for (int i = beg; i < end; ++i) {
        int g = batch[i];
        if (g != curg) {
            atomicAdd(&sums[(size_t)curg * 256 + c], acc);
            if (c == 0) atomicAdd(&counts[curg], runlen);
            acc = 0.f; runlen = 0; curg = g;
        }
        acc += bf2f(h[(size_t)i * 256 + c]);
        ++runlen;
    }
    atomicAdd(&sums[(size_t)curg * 256 + c], acc);
    if (c == 0) atomicAdd(&counts[curg], runlen);
}

__global__ __launch_bounds__(256) void pool_final_kernel(const float* __restrict__ sums,
                                                         const int* __restrict__ counts,
                                                         const float* __restrict__ Wout,
                                                         const float* __restrict__ bout,
                                                         float* __restrict__ out) {
    __shared__ float pl[256];
    int g = blockIdx.x;
    int c = threadIdx.x;
    int cnt = counts[g];
    pl[c] = sums[(size_t)g * 256 + c] / (float)(cnt > 0 ? cnt : 1);
    __syncthreads();
    if (c < 16) {
        float o = bout[c];
        #pragma unroll 4
        for (int k = 0; k < 256; ++k) o = fmaf(pl[k], Wout[k * 16 + c], o);
        out[g * 16 + c] = o;
    }
}

// ---------------- launch ----------------

extern "C" void kernel_launch(void* const* d_in, const int* in_sizes, int n_in,
                              void* d_out, int out_size, void* d_ws, size_t ws_size,
                              hipStream_t stream) {
    const float* x     = (const float*)d_in[0];
    const int*   ei    = (const int*)d_in[1];
    const int*   batch = (const int*)d_in[2];
    const float* W_in  = (const float*)d_in[3];
    const float* b_in  = (const float*)d_in[4];
    const float* W1    = (const float*)d_in[5];
    const float* b1    = (const float*)d_in[6];
    const float* W2    = (const float*)d_in[7];
    const float* b2    = (const float*)d_in[8];
    const float* Wout  = (const float*)d_in[9];
    const float* bout  = (const float*)d_in[10];

    const int E = in_sizes[1] / 2;
    const int N = in_sizes[2];
    const int IN_DIM = in_sizes[0] / N;   // 128
    const int G = 128;
    const int* src = ei;
    const int* dst = ei + E;

    char* ws = (char*)d_ws;
    size_t off = 0;
    auto alloc = [&](size_t bytes) { size_t p = off; off += (bytes + 255) & ~(size_t)255; return p; };
    unsigned short* bufA = (unsigned short*)(ws + alloc((size_t)N * 256 * 2));
    unsigned short* bufB = (unsigned short*)(ws + alloc((size_t)(N + 1) * 256 * 2)); // +1 zero row
    unsigned short* xb   = (unsigned short*)(ws + alloc((size_t)N * IN_DIM * 2));
    unsigned short* Wt2  = (unsigned short*)(ws + alloc((size_t)256 * 256 * 2));
    unsigned short* WfT  = (unsigned short*)(ws + alloc((size_t)256 * IN_DIM * 2));
    float*          bv   = (float*)(ws + alloc((size_t)256 * 4));
    float*          sbuf = (float*)(ws + alloc((size_t)N * 4));
    float* sums    = (float*)(ws + alloc((size_t)G * 256 * 4));
    int*   counts  = (int*)(ws + alloc((size_t)G * 4));
    size_t zbeg = off;
    int*   cursor  = (int*)(ws + alloc((size_t)N * 4));
    size_t zend = off;
    unsigned short* csr16 = (unsigned short*)(ws + alloc((size_t)N * 64 * 2));
    (void)ws_size;

    // ax aliases bufB's low region (dead until layer-2 gemm writes it); zero row beyond.
    unsigned short* axb = bufB;
    unsigned short* zrow = bufB + (size_t)N * 256;

    const int XB  = (N * IN_DIM / 4 + 255) / 256;
    const int WB  = 129;
    const int FB  = (E + 255) / 256;
    const int SB  = 129;   // sums+counts zeroing
    const int MB  = (N + 127) / 128;   // 391 gemm blocks

    hipMemsetAsync(ws + zbeg, 0, zend - zbeg, stream);   // cursor only (200 KB)
    fused_misc_kernel<<<FB + WB + 16 + 1 + SB + XB, 256, 0, stream>>>(
        W2, Wt2, x, xb, N * IN_DIM / 4, W_in, b_in, W1, WfT, bv,
        src, dst, cursor, csr16, zrow, sums, counts, E, FB, WB);

    // layer 1: aggregate raw x (128-wide), then one fused GEMM with relu epilogue
    agg_x_kernel<<<(N + 3) / 4, 256, 0, stream>>>(xb, cursor, csr16, axb, sbuf, N);
    gemm_bf16<2><<<MB, 512, 0, stream>>>(axb, WfT, sbuf, bv, b1, bufA, N, IN_DIM);

    // layer 2: gemm (deg-normalized epilogue) then aggregation with relu+bias
    gemm_bf16<1><<<MB, 512, 0, stream>>>(bufA, Wt2, (const float*)cursor, nullptr, nullptr, bufB, N, 256);
    agg_kernel<<<(N + 3) / 4, 256, 0, stream>>>(bufB, cursor, csr16, b2, bufA, N);

    const int PBLOCKS = 512;
    int chunk = (N + PBLOCKS - 1) / PBLOCKS;
    pool_partial_kernel<<<PBLOCKS, 256, 0, stream>>>(bufA, batch, sums, counts, N, chunk);
    pool_final_kernel<<<G, 256, 0, stream>>>(sums, counts, Wout, bout, (float*)d_out);
}